// Round 1
// baseline (602.585 us; speedup 1.0000x reference)
//
#include <hip/hip_runtime.h>
#include <hip/hip_bf16.h>

// ---- problem geometry ----
#define NROWS   131072          // 32*4096
#define DIM     64
#define NEMB    512
// output offsets (floats)
#define OUT_Q     0
#define OUT_DIFF  8388608
#define OUT_IND   8388609
#define OUT_OH    8519681      // 8388609 + 131072
#define OUT_ES    8520193      // OUT_OH + 512
// ws layout (floats)
#define WS_EN     0
#define WS_ET     512          // embedT [512][64]
#define WS_PART   33280        // 512 + 32768

__global__ __launch_bounds__(256) void vq_prep(const float* __restrict__ embed,
                                               float* __restrict__ ws,
                                               float* __restrict__ out, int P) {
  const int tid = blockIdx.x * blockDim.x + threadIdx.x;
  const int nth = gridDim.x * blockDim.x;
  // embedT[j][d] = embed[d][j]
  for (int e = tid; e < NEMB * DIM; e += nth) {
    int j = e >> 6, d = e & 63;
    ws[WS_ET + e] = embed[d * NEMB + j];
  }
  // en[j] = sum_d embed[d][j]^2
  for (int j = tid; j < NEMB; j += nth) {
    float s = 0.f;
    for (int d = 0; d < DIM; ++d) {
      float v = embed[d * NEMB + j];
      s = fmaf(v, v, s);
    }
    ws[WS_EN + j] = s;
  }
  // zero accumulator output regions (diff, onehot, embed_sum)
  if (tid == 0) out[OUT_DIFF] = 0.f;
  for (int e = tid; e < NEMB + NEMB * DIM; e += nth) out[OUT_OH + e] = 0.f;
  // zero ws partials
  for (long e = tid; e < (long)P * (NEMB * DIM); e += nth) ws[WS_PART + e] = 0.f;
}

__global__ __launch_bounds__(256) void vq_main(const float* __restrict__ input,
                                               const float* __restrict__ embed,
                                               const float* __restrict__ ws,
                                               float* __restrict__ ws_part,
                                               float* __restrict__ out, int P) {
  const int i = blockIdx.x * 256 + threadIdx.x;   // row index
  float x[DIM];
  const float4* xin = reinterpret_cast<const float4*>(input + (size_t)i * DIM);
#pragma unroll
  for (int k = 0; k < 16; ++k) {
    float4 v = xin[k];
    x[4 * k + 0] = v.x; x[4 * k + 1] = v.y; x[4 * k + 2] = v.z; x[4 * k + 3] = v.w;
  }
  float xx = 0.f;
#pragma unroll
  for (int d = 0; d < DIM; ++d) xx = fmaf(x[d], x[d], xx);

  float best = 3.4e38f;
  int   bj   = 0;
  for (int jt = 0; jt < NEMB; jt += 8) {
    float acc[8];
#pragma unroll
    for (int u = 0; u < 8; ++u) acc[u] = 0.f;
#pragma unroll 8
    for (int d = 0; d < DIM; ++d) {
      float xv = x[d];
#pragma unroll
      for (int u = 0; u < 8; ++u)
        acc[u] = fmaf(xv, embed[d * NEMB + jt + u], acc[u]);   // uniform -> s_load
    }
#pragma unroll
    for (int u = 0; u < 8; ++u) {
      float dist = (xx - 2.0f * acc[u]) + ws[WS_EN + jt + u];  // matches np expr order
      if (dist < best) { best = dist; bj = jt + u; }
    }
  }

  // embed_ind (as float)
  out[OUT_IND + i] = (float)bj;

  // quantize row + diff partial
  const float4* qr = reinterpret_cast<const float4*>(ws + WS_ET + (size_t)bj * DIM);
  float4* qo = reinterpret_cast<float4*>(out + (size_t)i * DIM);
  float dsum = 0.f;
#pragma unroll
  for (int k = 0; k < 16; ++k) {
    float4 q = qr[k];
    float e0 = q.x - x[4 * k + 0]; dsum = fmaf(e0, e0, dsum);
    float e1 = q.y - x[4 * k + 1]; dsum = fmaf(e1, e1, dsum);
    float e2 = q.z - x[4 * k + 2]; dsum = fmaf(e2, e2, dsum);
    float e3 = q.w - x[4 * k + 3]; dsum = fmaf(e3, e3, dsum);
    qo[k] = q;
  }

  // block-reduce diff
  __shared__ float red[256];
  red[threadIdx.x] = dsum;
  __syncthreads();
#pragma unroll
  for (int s = 128; s > 0; s >>= 1) {
    if (threadIdx.x < s) red[threadIdx.x] += red[threadIdx.x + s];
    __syncthreads();
  }
  if (threadIdx.x == 0)
    atomicAdd(out + OUT_DIFF, red[0] * (1.0f / (float)(NROWS * DIM)));

  // onehot
  atomicAdd(out + OUT_OH + bj, 1.0f);

  // embed_sum scatter (into partial copies to cut contention)
  float* es = (P > 0) ? (ws_part + (size_t)(blockIdx.x % P) * (NEMB * DIM))
                      : (out + OUT_ES);
#pragma unroll 4
  for (int d = 0; d < DIM; ++d) atomicAdd(es + d * NEMB + bj, x[d]);
}

__global__ __launch_bounds__(256) void vq_reduce(const float* __restrict__ ws_part,
                                                 float* __restrict__ out, int P) {
  const int e = blockIdx.x * 256 + threadIdx.x;
  if (e < NEMB * DIM) {
    float s = 0.f;
    for (int p = 0; p < P; ++p) s += ws_part[(size_t)p * (NEMB * DIM) + e];
    out[OUT_ES + e] = s;
  }
}

extern "C" void kernel_launch(void* const* d_in, const int* in_sizes, int n_in,
                              void* d_out, int out_size, void* d_ws, size_t ws_size,
                              hipStream_t stream) {
  const float* input = (const float*)d_in[0];
  const float* embed = (const float*)d_in[1];
  float* out = (float*)d_out;
  float* ws  = (float*)d_ws;

  long ws_floats = (long)(ws_size / 4);
  long avail = ws_floats - WS_PART;
  int P = 0;
  if (avail > 0) {
    long p = avail / (NEMB * DIM);
    P = (int)(p > 32 ? 32 : p);
  }
  float* ws_part = ws + WS_PART;

  vq_prep<<<128, 256, 0, stream>>>(embed, ws, out, P);
  vq_main<<<NROWS / 256, 256, 0, stream>>>(input, embed, ws, ws_part, out, P);
  if (P > 0) vq_reduce<<<(NEMB * DIM + 255) / 256, 256, 0, stream>>>(ws_part, out, P);
}

// Round 2
// 544.986 us; speedup vs baseline: 1.1057x; 1.1057x over previous
//
#include <hip/hip_runtime.h>
#include <hip/hip_bf16.h>

// ---- problem geometry ----
#define NROWS   131072          // 32*4096
#define DIM     64
#define NEMB    512
// output offsets (floats)
#define OUT_Q     0
#define OUT_DIFF  8388608
#define OUT_IND   8388609
#define OUT_OH    8519681      // 8388609 + 131072
#define OUT_ES    8520193      // OUT_OH + 512
// ws layout (floats)
#define WS_EN     0
#define WS_ET     512          // embedT [512][64]
#define WS_PART   33280        // 512 + 32768

__global__ __launch_bounds__(256) void vq_prep(const float* __restrict__ embed,
                                               float* __restrict__ ws,
                                               float* __restrict__ out, int P) {
  const int tid = blockIdx.x * blockDim.x + threadIdx.x;
  const int nth = gridDim.x * blockDim.x;
  // embedT[j][d] = embed[d][j]
  for (int e = tid; e < NEMB * DIM; e += nth) {
    int j = e >> 6, d = e & 63;
    ws[WS_ET + e] = embed[d * NEMB + j];
  }
  // en[j] = sum_d embed[d][j]^2
  for (int j = tid; j < NEMB; j += nth) {
    float s = 0.f;
    for (int d = 0; d < DIM; ++d) {
      float v = embed[d * NEMB + j];
      s = fmaf(v, v, s);
    }
    ws[WS_EN + j] = s;
  }
  // zero accumulator output regions (diff, onehot, embed_sum)
  if (tid == 0) out[OUT_DIFF] = 0.f;
  for (int e = tid; e < NEMB + NEMB * DIM; e += nth) out[OUT_OH + e] = 0.f;
  // zero ws partials
  for (long e = tid; e < (long)P * (NEMB * DIM); e += nth) ws[WS_PART + e] = 0.f;
}

__global__ __launch_bounds__(256) void vq_main(const float* __restrict__ input,
                                               const float* __restrict__ embed,
                                               const float* __restrict__ ws,
                                               float* __restrict__ ws_part,
                                               float* __restrict__ out, int P) {
  const int i = blockIdx.x * 256 + threadIdx.x;   // row index

  // x[] must stay in VGPRs: EVERY access below uses a compile-time index
  // (rule #20: any runtime index demotes the whole array to scratch).
  float x[DIM];
  const float4* xin = reinterpret_cast<const float4*>(input + (size_t)i * DIM);
#pragma unroll
  for (int k = 0; k < 16; ++k) {
    float4 v = xin[k];
    x[4 * k + 0] = v.x; x[4 * k + 1] = v.y; x[4 * k + 2] = v.z; x[4 * k + 3] = v.w;
  }
  float xx = 0.f;
#pragma unroll
  for (int d = 0; d < DIM; ++d) xx = fmaf(x[d], x[d], xx);

  float best = 3.4e38f;
  int   bj   = 0;
  for (int jt = 0; jt < NEMB; jt += 8) {
    float acc[8];
#pragma unroll
    for (int u = 0; u < 8; ++u) acc[u] = 0.f;
    // FULL unroll: d is a compile-time constant in every x[d]
#pragma unroll
    for (int d = 0; d < DIM; ++d) {
      const float xv = x[d];
#pragma unroll
      for (int u = 0; u < 8; ++u)
        acc[u] = fmaf(xv, embed[d * NEMB + jt + u], acc[u]);   // wave-uniform addr
    }
#pragma unroll
    for (int u = 0; u < 8; ++u) {
      float dist = (xx - 2.0f * acc[u]) + ws[WS_EN + jt + u];  // matches np expr order
      if (dist < best) { best = dist; bj = jt + u; }
    }
  }

  // embed_ind (as float)
  out[OUT_IND + i] = (float)bj;

  // quantize row + diff partial
  const float4* qr = reinterpret_cast<const float4*>(ws + WS_ET + (size_t)bj * DIM);
  float4* qo = reinterpret_cast<float4*>(out + (size_t)i * DIM);
  float dsum = 0.f;
#pragma unroll
  for (int k = 0; k < 16; ++k) {
    float4 q = qr[k];
    float e0 = q.x - x[4 * k + 0]; dsum = fmaf(e0, e0, dsum);
    float e1 = q.y - x[4 * k + 1]; dsum = fmaf(e1, e1, dsum);
    float e2 = q.z - x[4 * k + 2]; dsum = fmaf(e2, e2, dsum);
    float e3 = q.w - x[4 * k + 3]; dsum = fmaf(e3, e3, dsum);
    qo[k] = q;
  }

  // block-reduce diff
  __shared__ float red[256];
  red[threadIdx.x] = dsum;
  __syncthreads();
#pragma unroll
  for (int s = 128; s > 0; s >>= 1) {
    if (threadIdx.x < s) red[threadIdx.x] += red[threadIdx.x + s];
    __syncthreads();
  }
  if (threadIdx.x == 0)
    atomicAdd(out + OUT_DIFF, red[0] * (1.0f / (float)(NROWS * DIM)));

  // onehot
  atomicAdd(out + OUT_OH + bj, 1.0f);

  // embed_sum scatter (into partial copies to cut contention)
  // FULL unroll so x[d] stays const-indexed (registers, not scratch)
  float* es = (P > 0) ? (ws_part + (size_t)(blockIdx.x % P) * (NEMB * DIM))
                      : (out + OUT_ES);
#pragma unroll
  for (int d = 0; d < DIM; ++d) atomicAdd(es + d * NEMB + bj, x[d]);
}

__global__ __launch_bounds__(256) void vq_reduce(const float* __restrict__ ws_part,
                                                 float* __restrict__ out, int P) {
  const int e = blockIdx.x * 256 + threadIdx.x;
  if (e < NEMB * DIM) {
    float s = 0.f;
    for (int p = 0; p < P; ++p) s += ws_part[(size_t)p * (NEMB * DIM) + e];
    out[OUT_ES + e] = s;
  }
}

extern "C" void kernel_launch(void* const* d_in, const int* in_sizes, int n_in,
                              void* d_out, int out_size, void* d_ws, size_t ws_size,
                              hipStream_t stream) {
  const float* input = (const float*)d_in[0];
  const float* embed = (const float*)d_in[1];
  float* out = (float*)d_out;
  float* ws  = (float*)d_ws;

  long ws_floats = (long)(ws_size / 4);
  long avail = ws_floats - WS_PART;
  int P = 0;
  if (avail > 0) {
    long p = avail / (NEMB * DIM);
    P = (int)(p > 32 ? 32 : p);
  }
  float* ws_part = ws + WS_PART;

  vq_prep<<<128, 256, 0, stream>>>(embed, ws, out, P);
  vq_main<<<NROWS / 256, 256, 0, stream>>>(input, embed, ws, ws_part, out, P);
  if (P > 0) vq_reduce<<<(NEMB * DIM + 255) / 256, 256, 0, stream>>>(ws_part, out, P);
}